// Round 1
// baseline (392.910 us; speedup 1.0000x reference)
//
#include <hip/hip_runtime.h>

// Conv1d: x (32, 64, 16384) f32, w (64, 64, 3) f32, bias (64) f32
// -> out (32, 64, 16382) f32, VALID, stride 1.
// GEMM view: out[co][n] = sum_kappa A[co][kappa] * B[kappa][n] + bias[co]
//   kappa = kk*64 + ci (kk-major). B[kappa][n] = x[ci][n+kk].
// KEY: for fixed (ci, n) the three kk values are CONTIGUOUS in x -> one
// dwordx4 load per (ci, col) feeds all 3 kk fragments of the same lane.
// 192 scalar loads/lane -> 64 dwordx4 loads/lane; manual RNE f2bf ->
// native casts (v_cvt_pk_bf16_f32). Weights staged kappa-major in LDS.

typedef __bf16 bf16x8 __attribute__((ext_vector_type(8)));
typedef float f32x16 __attribute__((ext_vector_type(16)));
typedef float f32x4u __attribute__((ext_vector_type(4), aligned(4)));  // 4B-aligned vec load

#define C_IN 64
#define C_OUT 64
#define L_IN 16384
#define L_OUT 16382
#define NT 256          // n-columns per block
#define PW 200          // wl row pitch (elems); keeps 16B align, no conflicts (measured 0)

__device__ __forceinline__ unsigned short f2bf(float f) {
  unsigned u = __builtin_bit_cast(unsigned, f);
  return (unsigned short)((u + 0x7FFFu + ((u >> 16) & 1u)) >> 16);  // RNE
}

__global__ __launch_bounds__(256, 4) void conv1d_mfma(
    const float* __restrict__ x, const float* __restrict__ w,
    const float* __restrict__ bias, float* __restrict__ out) {
  __shared__ __align__(16) unsigned short wl[C_OUT * PW];  // 25600 B
  __shared__ float bias_s[C_OUT];

  const int t = threadIdx.x;
  const int bx = blockIdx.x;
  const int b = bx >> 6;        // batch
  const int tile = bx & 63;     // l-tile
  const int l0 = tile * NT;

  // ---- weights -> LDS bf16, layout wl[co][kk*64 + ci] (kappa-order)
  for (int i = t; i < C_OUT * 192; i += 256) {
    int co = i / 192;
    int r = i - co * 192;
    int ci = r / 3;
    int kk = r - ci * 3;
    wl[co * PW + kk * 64 + ci] = f2bf(w[i]);
  }
  if (t < C_OUT) bias_s[t] = bias[t];
  __syncthreads();

  // ---- MFMA main loop: wave wv owns n in [wv*64, wv*64+64), all 64 co
  const int lane = t & 63;
  const int wv = t >> 6;
  const int half = lane >> 5;   // k-half within fragment
  const int ln = lane & 31;
  const int kh = half * 8;
  const int n0 = wv * 64 + ln;
  const int l_a = l0 + n0;      // column for b0 fragments

  const float* xb = x + (size_t)b * (C_IN * L_IN);

  f32x16 acc00 = {}, acc01 = {}, acc10 = {}, acc11 = {};

  if (!(tile == 63 && wv == 3)) {
    // ---- FAST PATH: dwordx4 per (ci, col) gives kk=0,1,2 in-lane.
    // Per half: 4 ci-groups of 8; fragment (g,kk) has kappa = kk*64 + g*16 + kh + jj.
    // No clamping needed: max touched col = l_a+32+3 <= 16354 here.
#pragma unroll
    for (int g = 0; g < 4; ++g) {
      const int ci0 = g * 16 + kh;
      const float* pbase = xb + (size_t)ci0 * L_IN + l_a;
#pragma unroll
      for (int c = 0; c < 2; ++c) {   // two column halves: l_a, l_a+32
        f32x4u v[8];
#pragma unroll
        for (int jj = 0; jj < 8; ++jj)
          v[jj] = *(const f32x4u*)(pbase + jj * L_IN + c * 32);
        bf16x8 bf0, bf1, bf2;
#pragma unroll
        for (int jj = 0; jj < 8; ++jj) {
          bf0[jj] = (__bf16)v[jj][0];   // kk = 0
          bf1[jj] = (__bf16)v[jj][1];   // kk = 1
          bf2[jj] = (__bf16)v[jj][2];   // kk = 2
        }
#pragma unroll
        for (int kk = 0; kk < 3; ++kk) {
          bf16x8 a0 = *(const bf16x8*)&wl[ln * PW + kk * 64 + g * 16 + kh];
          bf16x8 a1 = *(const bf16x8*)&wl[(32 + ln) * PW + kk * 64 + g * 16 + kh];
          bf16x8 bb = (kk == 0) ? bf0 : ((kk == 1) ? bf1 : bf2);
          if (c == 0) {
            acc00 = __builtin_amdgcn_mfma_f32_32x32x16_bf16(a0, bb, acc00, 0, 0, 0);
            acc10 = __builtin_amdgcn_mfma_f32_32x32x16_bf16(a1, bb, acc10, 0, 0, 0);
          } else {
            acc01 = __builtin_amdgcn_mfma_f32_32x32x16_bf16(a0, bb, acc01, 0, 0, 0);
            acc11 = __builtin_amdgcn_mfma_f32_32x32x16_bf16(a1, bb, acc11, 0, 0, 0);
          }
        }
      }
    }
  } else {
    // ---- SLOW PATH (tile 63, wave 3 only — 32 of 8192 waves): scalar
    // clamped loads; dwordx4 here would read past the end of x.
#pragma unroll
    for (int s = 0; s < 12; ++s) {
      bf16x8 a0 = *(const bf16x8*)&wl[ln * PW + s * 16 + kh];
      bf16x8 a1 = *(const bf16x8*)&wl[(32 + ln) * PW + s * 16 + kh];
      int tt = s * 16 + kh;
      int kk = tt >> 6;           // uniform over the 8-elem fragment
      int ci0 = tt & 63;
      int p0 = min(l_a + kk, L_IN - 1);
      int p1 = min(l_a + 32 + kk, L_IN - 1);
      const float* base = xb + (size_t)ci0 * L_IN;
      bf16x8 b0, b1;
#pragma unroll
      for (int jj = 0; jj < 8; ++jj) {
        b0[jj] = (__bf16)base[(size_t)jj * L_IN + p0];
        b1[jj] = (__bf16)base[(size_t)jj * L_IN + p1];
      }
      acc00 = __builtin_amdgcn_mfma_f32_32x32x16_bf16(a0, b0, acc00, 0, 0, 0);
      acc01 = __builtin_amdgcn_mfma_f32_32x32x16_bf16(a0, b1, acc01, 0, 0, 0);
      acc10 = __builtin_amdgcn_mfma_f32_32x32x16_bf16(a1, b0, acc10, 0, 0, 0);
      acc11 = __builtin_amdgcn_mfma_f32_32x32x16_bf16(a1, b1, acc11, 0, 0, 0);
    }
  }

  // ---- epilogue: C/D layout col = lane&31, row = (r&3) + 8*(r>>2) + 4*half
  const int l_base = l0 + wv * 64 + ln;
  const bool full = (l0 + NT <= L_OUT);  // only last tile needs guards
  if (full) {
#pragma unroll
    for (int mt = 0; mt < 2; ++mt) {
#pragma unroll
      for (int r = 0; r < 16; ++r) {
        int co = mt * 32 + 4 * half + (r & 3) + 8 * (r >> 2);
        float bv = bias_s[co];
        size_t row = ((size_t)b * C_OUT + co) * (size_t)L_OUT;
        float v0 = (mt == 0 ? acc00[r] : acc10[r]) + bv;
        float v1 = (mt == 0 ? acc01[r] : acc11[r]) + bv;
        out[row + l_base] = v0;
        out[row + l_base + 32] = v1;
      }
    }
  } else {
#pragma unroll
    for (int mt = 0; mt < 2; ++mt) {
#pragma unroll
      for (int r = 0; r < 16; ++r) {
        int co = mt * 32 + 4 * half + (r & 3) + 8 * (r >> 2);
        float bv = bias_s[co];
        size_t row = ((size_t)b * C_OUT + co) * (size_t)L_OUT;
        float v0 = (mt == 0 ? acc00[r] : acc10[r]) + bv;
        float v1 = (mt == 0 ? acc01[r] : acc11[r]) + bv;
        if (l_base < L_OUT) out[row + l_base] = v0;
        if (l_base + 32 < L_OUT) out[row + l_base + 32] = v1;
      }
    }
  }
}

extern "C" void kernel_launch(void* const* d_in, const int* in_sizes, int n_in,
                              void* d_out, int out_size, void* d_ws, size_t ws_size,
                              hipStream_t stream) {
  const float* x = (const float*)d_in[0];
  const float* w = (const float*)d_in[1];
  const float* bias = (const float*)d_in[2];
  float* out = (float*)d_out;
  // 32 batches * 64 l-tiles of 256 columns
  conv1d_mfma<<<dim3(32 * 64), dim3(256), 0, stream>>>(x, w, bias, out);
}